// Round 13
// baseline (193.125 us; speedup 1.0000x reference)
//
#include <hip/hip_runtime.h>

#define BB 32768
#define FF 16
#define HH 64
#define OO 32
#define EE 16

// fp32 -> bf16 pair pack (RNE), and bf16 -> fp32 unpack (exact)
__device__ __forceinline__ unsigned bfpack(float lo, float hi) {
    unsigned a = __float_as_uint(lo), b = __float_as_uint(hi);
    a = (a + 0x7FFFu + ((a >> 16) & 1u)) >> 16;
    b = (b + 0x7FFFu + ((b >> 16) & 1u)) >> 16;
    return a | (b << 16);
}
__device__ __forceinline__ float bflo(unsigned u) { return __uint_as_float(u << 16); }
__device__ __forceinline__ float bfhi(unsigned u) { return __uint_as_float(u & 0xFFFF0000u); }

// ---------------- Kernel 0: W3p = W3 @ Wp, bp3 = b3 @ Wp + bp (per feature) ----
__global__ __launch_bounds__(256) void w3p_kernel(
    const float* __restrict__ W3, const float* __restrict__ b3,
    const float* __restrict__ Wp, const float* __restrict__ bp,
    float* __restrict__ w3p, float* __restrict__ bp3)
{
    const int f = blockIdx.x, t = threadIdx.x;
    const float* __restrict__ w3f = W3 + f*HH*OO;
    #pragma unroll
    for (int r = 0; r < 4; ++r) {
        const int idx = t*4 + r;            // 0..1023 -> (j = idx>>4, e = idx&15)
        const int j = idx >> 4, e = idx & 15;
        float acc = 0.f;
        #pragma unroll
        for (int o = 0; o < OO; ++o)
            acc = fmaf(w3f[j*OO + o], Wp[o*EE + e], acc);
        w3p[f*1024 + idx] = acc;
    }
    if (t < EE) {
        float acc = bp[t];
        #pragma unroll
        for (int o = 0; o < OO; ++o)
            acc = fmaf(b3[f*OO + o], Wp[o*EE + t], acc);
        bp3[f*EE + t] = acc;
    }
}

// ---------------- Phase 1: per-feature subnets -> tok(bf16) [B][F][E] ----------
// Round-12 structure (co-location remap, W3p fold, k-chunking, bf16 tok).
// Round-13 A/B: scalar v_fmac (VOP2, direct SGPR weight operand -- no s->v movs)
// instead of v_pk_fma (VOP3P, suspected 2x v_mov bloat = the 60us VALU busy),
// plus j-loop unroll 4 for deeper s_load prefetch. Math bit-identical to r12.
__global__ __launch_bounds__(256, 4) void spinn_subnet_kernel(
    const float* __restrict__ x,
    const float* __restrict__ W1, const float* __restrict__ b1,
    const float* __restrict__ W2, const float* __restrict__ b2,
    const float* __restrict__ w3p, const float* __restrict__ bp3,
    unsigned* __restrict__ tokb)
{
    const int g  = blockIdx.x;
    const int f  = g & 15;                               // same-CU blocks share f
    const int mt = ((g >> 8) << 4) | ((g & 255) >> 4);   // batch tile, bijective
    const int t  = threadIdx.x;
    const int b  = mt * 256 + t;

    const float* __restrict__ w1   = W1  + f*HH;      // [64]
    const float* __restrict__ bb1  = b1  + f*HH;
    const float* __restrict__ w2   = W2  + f*HH*HH;   // [64][64]
    const float* __restrict__ bb2  = b2  + f*HH;
    const float* __restrict__ w3pf = w3p + f*HH*EE;   // [64][16] folded W3@Wp
    const float* __restrict__ bp3f = bp3 + f*EE;

    const float xv = x[(size_t)b*FF + f];

    float te[EE];                                     // folded layer3+proj acc
    #pragma unroll
    for (int e = 0; e < EE; ++e) te[e] = bp3f[e];

    #pragma unroll
    for (int c = 0; c < 2; ++c) {
        const int k0 = c*32;
        float hc[32];                                 // h2 chunk [k0, k0+32)
        #pragma unroll
        for (int k = 0; k < 32; ++k) hc[k] = bb2[k0 + k];

        #pragma unroll 4
        for (int j = 0; j < HH; ++j) {
            float h1 = fmaf(xv, w1[j], bb1[j]);
            h1 = (h1 >= 0.f) ? h1 : 0.01f*h1;
            const float* wr = w2 + j*HH + k0;         // uniform -> s_load
            #pragma unroll
            for (int k = 0; k < 32; ++k)
                hc[k] = fmaf(h1, wr[k], hc[k]);       // v_fmac v, s, v
        }

        // leaky + fold chunk into te via W3p (static indexing throughout)
        #pragma unroll
        for (int k = 0; k < 32; ++k) {
            float hv = hc[k];
            hv = (hv >= 0.f) ? hv : 0.01f*hv;
            const float* wr3 = w3pf + (k0 + k)*EE;    // uniform -> s_load
            #pragma unroll
            for (int e = 0; e < EE; ++e)
                te[e] = fmaf(hv, wr3[e], te[e]);
        }
    }

    // write tok row (bf16, 32 B contiguous)
    unsigned* row = tokb + ((size_t)b*FF + (size_t)f)*(EE/2);
    uint4 p0, p1;
    p0.x = bfpack(te[0],  te[1]);  p0.y = bfpack(te[2],  te[3]);
    p0.z = bfpack(te[4],  te[5]);  p0.w = bfpack(te[6],  te[7]);
    p1.x = bfpack(te[8],  te[9]);  p1.y = bfpack(te[10], te[11]);
    p1.z = bfpack(te[12], te[13]); p1.w = bfpack(te[14], te[15]);
    ((uint4*)row)[0] = p0;
    ((uint4*)row)[1] = p1;
}

// ---------------- Phase 2: qkv + attention + pool + final FC ----------------
// UNCHANGED from round 12.
#define KVPAD 260   // floats per batch row: 256 + 4 pad

__device__ __forceinline__ float sum16(float v) {
    int i;
    i = __builtin_amdgcn_update_dpp(0, __float_as_int(v), 0xB1,  0xF, 0xF, true); v += __int_as_float(i); // xor 1
    i = __builtin_amdgcn_update_dpp(0, __float_as_int(v), 0x4E,  0xF, 0xF, true); v += __int_as_float(i); // xor 2
    i = __builtin_amdgcn_update_dpp(0, __float_as_int(v), 0x141, 0xF, 0xF, true); v += __int_as_float(i); // half-mirror
    i = __builtin_amdgcn_update_dpp(0, __float_as_int(v), 0x140, 0xF, 0xF, true); v += __int_as_float(i); // row mirror
    return v;
}

__global__ __launch_bounds__(256, 4) void spinn_attn_kernel(
    const unsigned* __restrict__ tokb,
    const float* __restrict__ Wqkv, const float* __restrict__ bqkv,
    const float* __restrict__ Wo,   const float* __restrict__ bo,
    const float* __restrict__ Wf,   const float* __restrict__ bf,
    float* __restrict__ out)
{
    __shared__ __align__(16) float kb[16*KVPAD];
    __shared__ __align__(16) float vb[16*KVPAD];

    const int t  = threadIdx.x;
    const int f  = t & 15;        // token index (16-lane group)
    const int bl = t >> 4;        // local batch 0..15
    const int gb = blockIdx.x * 16 + bl;

    float tokv[EE];
    {
        const uint4* tp = (const uint4*)(tokb + ((size_t)gb*FF + (size_t)f)*(EE/2));
        uint4 u0 = tp[0], u1 = tp[1];
        tokv[0]  = bflo(u0.x); tokv[1]  = bfhi(u0.x);
        tokv[2]  = bflo(u0.y); tokv[3]  = bfhi(u0.y);
        tokv[4]  = bflo(u0.z); tokv[5]  = bfhi(u0.z);
        tokv[6]  = bflo(u0.w); tokv[7]  = bfhi(u0.w);
        tokv[8]  = bflo(u1.x); tokv[9]  = bfhi(u1.x);
        tokv[10] = bflo(u1.y); tokv[11] = bfhi(u1.y);
        tokv[12] = bflo(u1.z); tokv[13] = bfhi(u1.z);
        tokv[14] = bflo(u1.w); tokv[15] = bfhi(u1.w);
    }

    // ---- pass A: q (regs) + k (-> LDS)
    float q[EE], kx[EE];
    #pragma unroll
    for (int i = 0; i < EE; ++i) { q[i] = bqkv[i]; kx[i] = bqkv[EE + i]; }
    #pragma unroll
    for (int e = 0; e < EE; ++e) {
        const float tv = tokv[e];
        #pragma unroll
        for (int i = 0; i < EE; ++i) {
            q[i]  = fmaf(tv, Wqkv[e*48 + i],      q[i]);
            kx[i] = fmaf(tv, Wqkv[e*48 + EE + i], kx[i]);
        }
    }
    {
        float4* kr = (float4*)(kb + bl*KVPAD + f*16);
        kr[0] = make_float4(kx[0],  kx[1],  kx[2],  kx[3]);
        kr[1] = make_float4(kx[4],  kx[5],  kx[6],  kx[7]);
        kr[2] = make_float4(kx[8],  kx[9],  kx[10], kx[11]);
        kr[3] = make_float4(kx[12], kx[13], kx[14], kx[15]);
    }

    // ---- pass B: v (-> LDS)
    {
        float vx[EE];
        #pragma unroll
        for (int i = 0; i < EE; ++i) vx[i] = bqkv[2*EE + i];
        #pragma unroll
        for (int e = 0; e < EE; ++e) {
            const float tv = tokv[e];
            #pragma unroll
            for (int i = 0; i < EE; ++i)
                vx[i] = fmaf(tv, Wqkv[e*48 + 2*EE + i], vx[i]);
        }
        float4* vr = (float4*)(vb + bl*KVPAD + f*16);
        vr[0] = make_float4(vx[0],  vx[1],  vx[2],  vx[3]);
        vr[1] = make_float4(vx[4],  vx[5],  vx[6],  vx[7]);
        vr[2] = make_float4(vx[8],  vx[9],  vx[10], vx[11]);
        vr[3] = make_float4(vx[12], vx[13], vx[14], vx[15]);
    }

    // ---- scores vs all 16 k rows, scale 0.25
    float s[16];
    #pragma unroll
    for (int kk = 0; kk < 16; ++kk) {
        const float4* krow = (const float4*)(kb + bl*KVPAD + kk*16);
        float4 k0 = krow[0], k1 = krow[1], k2 = krow[2], k3 = krow[3];
        float d = q[0]*k0.x  + q[1]*k0.y  + q[2]*k0.z  + q[3]*k0.w
                + q[4]*k1.x  + q[5]*k1.y  + q[6]*k1.z  + q[7]*k1.w
                + q[8]*k2.x  + q[9]*k2.y  + q[10]*k2.z + q[11]*k2.w
                + q[12]*k3.x + q[13]*k3.y + q[14]*k3.z + q[15]*k3.w;
        s[kk] = d * 0.25f;
    }

    // ---- stable softmax
    float m = s[0];
    #pragma unroll
    for (int kk = 1; kk < 16; ++kk) m = fmaxf(m, s[kk]);
    float sum = 0.f;
    #pragma unroll
    for (int kk = 0; kk < 16; ++kk) { s[kk] = __expf(s[kk] - m); sum += s[kk]; }
    const float inv = 1.0f / sum;
    #pragma unroll
    for (int kk = 0; kk < 16; ++kk) s[kk] *= inv;

    // ---- column sums across 16 token-lanes -> 16*abar (replicated)
    #pragma unroll
    for (int kk = 0; kk < 16; ++kk) s[kk] = sum16(s[kk]);

    // ---- pooled_v[f]
    float pvf = 0.f;
    #pragma unroll
    for (int kk = 0; kk < 16; ++kk)
        pvf = fmaf(s[kk], vb[bl*KVPAD + kk*16 + f], pvf);
    pvf *= 0.0625f;

    // ---- wof[f] = Wo[f][:] . Wf
    float wof;
    {
        const float4* wr = (const float4*)(Wo + f*EE);
        float4 w0 = wr[0], w1 = wr[1], w2 = wr[2], w3 = wr[3];
        wof = w0.x*Wf[0]  + w0.y*Wf[1]  + w0.z*Wf[2]  + w0.w*Wf[3]
            + w1.x*Wf[4]  + w1.y*Wf[5]  + w1.z*Wf[6]  + w1.w*Wf[7]
            + w2.x*Wf[8]  + w2.y*Wf[9]  + w2.z*Wf[10] + w2.w*Wf[11]
            + w3.x*Wf[12] + w3.y*Wf[13] + w3.z*Wf[14] + w3.w*Wf[15];
    }

    float c = fmaf(pvf, wof, bo[f]*Wf[f]);
    c = sum16(c);

    if (f == 0) {
        float r = c + bf[0];
        out[gb] = (r >= 0.f) ? r : 0.01f*r;
    }
}

extern "C" void kernel_launch(void* const* d_in, const int* in_sizes, int n_in,
                              void* d_out, int out_size, void* d_ws, size_t ws_size,
                              hipStream_t stream)
{
    const float* x    = (const float*)d_in[0];
    const float* W1   = (const float*)d_in[1];
    const float* b1   = (const float*)d_in[2];
    const float* W2   = (const float*)d_in[3];
    const float* b2   = (const float*)d_in[4];
    const float* W3   = (const float*)d_in[5];
    const float* b3   = (const float*)d_in[6];
    const float* Wp   = (const float*)d_in[7];
    const float* bp   = (const float*)d_in[8];
    const float* Wqkv = (const float*)d_in[9];
    const float* bqkv = (const float*)d_in[10];
    const float* Wo   = (const float*)d_in[11];
    const float* bo   = (const float*)d_in[12];
    const float* Wf   = (const float*)d_in[13];
    const float* bf   = (const float*)d_in[14];
    float* out = (float*)d_out;

    // d_ws layout: [0,16MiB) tok bf16 [B][F][E]; at 16MiB: W3p fp32 (64KB) + bp3 (1KB)
    unsigned* tokb = (unsigned*)d_ws;
    float* w3p = (float*)((char*)d_ws + (16u << 20));
    float* bp3 = w3p + FF*HH*EE;

    w3p_kernel<<<FF, 256, 0, stream>>>(W3, b3, Wp, bp, w3p, bp3);
    spinn_subnet_kernel<<<dim3(BB/256 * FF), 256, 0, stream>>>(x, W1, b1, W2, b2, w3p, bp3, tokb);
    spinn_attn_kernel<<<BB/16, 256, 0, stream>>>(tokb, Wqkv, bqkv, Wo, bo, Wf, bf, out);
}

// Round 14
// 133.863 us; speedup vs baseline: 1.4427x; 1.4427x over previous
//
#include <hip/hip_runtime.h>

#define BB 32768
#define FF 16
#define HH 64
#define OO 32
#define EE 16

typedef _Float16 f16x8 __attribute__((ext_vector_type(8)));
typedef float f32x4 __attribute__((ext_vector_type(4)));
union U16x8 { uint4 u; f16x8 h; };

// fp32 -> bf16 (RNE) single, and bf16-pair unpack helpers (attn unchanged)
__device__ __forceinline__ unsigned short bf16of(float v) {
    unsigned u = __float_as_uint(v);
    u = (u + 0x7FFFu + ((u >> 16) & 1u)) >> 16;
    return (unsigned short)u;
}
__device__ __forceinline__ float bflo(unsigned u) { return __uint_as_float(u << 16); }
__device__ __forceinline__ float bfhi(unsigned u) { return __uint_as_float(u & 0xFFFF0000u); }

// ---------- Kernel 0: fold W3p = W3[f]@Wp (+bp3) and prepack W2, W3p into ----
// ---------- f16 MFMA B-fragment layout: slot (lane l, i) -> k = 8*(l>>4)+i ----
__global__ __launch_bounds__(256) void prepack_kernel(
    const float* __restrict__ W2, const float* __restrict__ W3,
    const float* __restrict__ b3, const float* __restrict__ Wp,
    const float* __restrict__ bp,
    uint4* __restrict__ w2h, uint4* __restrict__ w3ph, float* __restrict__ bp3)
{
    __shared__ float w3p[HH*EE];
    const int f = blockIdx.x, t = threadIdx.x;
    const float* __restrict__ w3f = W3 + f*HH*OO;
    #pragma unroll
    for (int r = 0; r < 4; ++r) {
        const int idx = t*4 + r;            // (j = idx>>4, e = idx&15)
        const int j = idx >> 4, e = idx & 15;
        float acc = 0.f;
        #pragma unroll
        for (int o = 0; o < OO; ++o)
            acc = fmaf(w3f[j*OO + o], Wp[o*EE + e], acc);
        w3p[idx] = acc;
    }
    if (t < EE) {
        float acc = bp[t];
        #pragma unroll
        for (int o = 0; o < OO; ++o)
            acc = fmaf(b3[f*OO + o], Wp[o*EE + t], acc);
        bp3[f*EE + t] = acc;
    }
    __syncthreads();

    // W2 B-frags: [f][ns = n*2+s][lane] ; B[k = s*32+8*(l>>4)+i][col n*16+(l&15)]
    for (int q = t; q < 512; q += 256) {
        const int ns = q >> 6, l = q & 63;
        const int n = ns >> 1, s = ns & 1, lg = l >> 4, col = l & 15;
        U16x8 u;
        #pragma unroll
        for (int i = 0; i < 8; ++i)
            u.h[i] = (_Float16)W2[(size_t)f*HH*HH + (s*32 + lg*8 + i)*HH + n*16 + col];
        w2h[((size_t)f*8 + ns)*64 + l] = u.u;
    }
    // W3p B-frags: [f][s][lane]
    if (t < 128) {
        const int s = t >> 6, l = t & 63, lg = l >> 4, col = l & 15;
        U16x8 u;
        #pragma unroll
        for (int i = 0; i < 8; ++i)
            u.h[i] = (_Float16)w3p[(s*32 + lg*8 + i)*EE + col];
        w3ph[((size_t)f*2 + s)*64 + l] = u.u;
    }
}

// ---------- Phase 1: per-feature subnets via f16 MFMA -> tok(bf16) [B][F][E] --
// Wave = 16 batches x 1 feature; 4 independent waves/block (no barriers).
// A1 computed per-lane directly in A-frag layout (row = l&15, k = 8*(l>>4)+i);
// h2 transposed through a small padded LDS tile; GEMM2 folds layer3+proj.
__global__ __launch_bounds__(256, 4) void spinn_subnet_mfma(
    const float* __restrict__ x,
    const float* __restrict__ W1, const float* __restrict__ b1,
    const float* __restrict__ b2,
    const uint4* __restrict__ w2h, const uint4* __restrict__ w3ph,
    const float* __restrict__ bp3,
    unsigned short* __restrict__ tokb16)
{
    __shared__ _Float16 h2l[4][16][72];   // per-wave 16x64 tile, +8 f16 row pad

    const int g   = blockIdx.x;
    const int f   = g & 15;                              // same-CU blocks share f
    const int mt  = ((g >> 8) << 4) | ((g >> 4) & 15);   // batch tile [0,512), bijective
    const int t   = threadIdx.x;
    const int wid = t >> 6, l = t & 63;
    const int lg  = l >> 4, col = l & 15;
    const int base = mt*64 + wid*16;
    const int brow = base + col;                         // this lane's A-row batch

    const float xv = x[(size_t)brow*FF + f];

    // ---- A1 frags (h1 in f16), kstep s: j = s*32 + lg*8 + i ----
    f16x8 a1[2];
    #pragma unroll
    for (int s = 0; s < 2; ++s) {
        const int j0 = s*32 + lg*8;
        const float4 wA = *(const float4*)(W1 + f*HH + j0);
        const float4 wB = *(const float4*)(W1 + f*HH + j0 + 4);
        const float4 bA = *(const float4*)(b1 + f*HH + j0);
        const float4 bB = *(const float4*)(b1 + f*HH + j0 + 4);
        float h;
        h = fmaf(xv, wA.x, bA.x); h = h>=0.f?h:0.01f*h; a1[s][0] = (_Float16)h;
        h = fmaf(xv, wA.y, bA.y); h = h>=0.f?h:0.01f*h; a1[s][1] = (_Float16)h;
        h = fmaf(xv, wA.z, bA.z); h = h>=0.f?h:0.01f*h; a1[s][2] = (_Float16)h;
        h = fmaf(xv, wA.w, bA.w); h = h>=0.f?h:0.01f*h; a1[s][3] = (_Float16)h;
        h = fmaf(xv, wB.x, bB.x); h = h>=0.f?h:0.01f*h; a1[s][4] = (_Float16)h;
        h = fmaf(xv, wB.y, bB.y); h = h>=0.f?h:0.01f*h; a1[s][5] = (_Float16)h;
        h = fmaf(xv, wB.z, bB.z); h = h>=0.f?h:0.01f*h; a1[s][6] = (_Float16)h;
        h = fmaf(xv, wB.w, bB.w); h = h>=0.f?h:0.01f*h; a1[s][7] = (_Float16)h;
    }

    // ---- GEMM1: c1[n] = A1 @ W2[:, n*16..+16)  (8 MFMA) ----
    f32x4 c1[4];
    const uint4* w2base = w2h + ((size_t)f*8)*64 + l;
    #pragma unroll
    for (int n = 0; n < 4; ++n) {
        U16x8 f0, f1;
        f0.u = w2base[(n*2 + 0)*64];
        f1.u = w2base[(n*2 + 1)*64];
        f32x4 c = {0.f, 0.f, 0.f, 0.f};
        c = __builtin_amdgcn_mfma_f32_16x16x32_f16(a1[0], f0.h, c, 0, 0, 0);
        c = __builtin_amdgcn_mfma_f32_16x16x32_f16(a1[1], f1.h, c, 0, 0, 0);
        c1[n] = c;
    }

    // ---- +b2, leaky, transpose via LDS (C layout: row = lg*4+r, col = col) ----
    #pragma unroll
    for (int n = 0; n < 4; ++n) {
        const float bias = b2[f*HH + n*16 + col];
        #pragma unroll
        for (int r = 0; r < 4; ++r) {
            float hv = c1[n][r] + bias;
            hv = hv >= 0.f ? hv : 0.01f*hv;
            h2l[wid][lg*4 + r][n*16 + col] = (_Float16)hv;
        }
    }

    // ---- A2 frags: row = col (batch), k = s*32 + lg*8 + i (16B ds_read) ----
    f16x8 a2[2];
    a2[0] = *(const f16x8*)&h2l[wid][col][lg*8];
    a2[1] = *(const f16x8*)&h2l[wid][col][32 + lg*8];

    // ---- GEMM2: te = h2 @ W3p (2 MFMA) ----
    U16x8 g0, g1;
    g0.u = w3ph[((size_t)f*2 + 0)*64 + l];
    g1.u = w3ph[((size_t)f*2 + 1)*64 + l];
    f32x4 c2 = {0.f, 0.f, 0.f, 0.f};
    c2 = __builtin_amdgcn_mfma_f32_16x16x32_f16(a2[0], g0.h, c2, 0, 0, 0);
    c2 = __builtin_amdgcn_mfma_f32_16x16x32_f16(a2[1], g1.h, c2, 0, 0, 0);

    // ---- +bp3, bf16 store: lane holds te[batch = base+lg*4+r][e = col] ----
    const float bias2 = bp3[f*EE + col];
    #pragma unroll
    for (int r = 0; r < 4; ++r) {
        const int b = base + lg*4 + r;
        tokb16[(size_t)b*(FF*EE) + f*EE + col] = bf16of(c2[r] + bias2);
    }
}

// ---------------- Phase 2: qkv + attention + pool + final FC ----------------
// UNCHANGED from round 12/13 (tok bf16 [B][F][E]).
#define KVPAD 260

__device__ __forceinline__ float sum16(float v) {
    int i;
    i = __builtin_amdgcn_update_dpp(0, __float_as_int(v), 0xB1,  0xF, 0xF, true); v += __int_as_float(i);
    i = __builtin_amdgcn_update_dpp(0, __float_as_int(v), 0x4E,  0xF, 0xF, true); v += __int_as_float(i);
    i = __builtin_amdgcn_update_dpp(0, __float_as_int(v), 0x141, 0xF, 0xF, true); v += __int_as_float(i);
    i = __builtin_amdgcn_update_dpp(0, __float_as_int(v), 0x140, 0xF, 0xF, true); v += __int_as_float(i);
    return v;
}

__global__ __launch_bounds__(256, 4) void spinn_attn_kernel(
    const unsigned* __restrict__ tokb,
    const float* __restrict__ Wqkv, const float* __restrict__ bqkv,
    const float* __restrict__ Wo,   const float* __restrict__ bo,
    const float* __restrict__ Wf,   const float* __restrict__ bf,
    float* __restrict__ out)
{
    __shared__ __align__(16) float kb[16*KVPAD];
    __shared__ __align__(16) float vb[16*KVPAD];

    const int t  = threadIdx.x;
    const int f  = t & 15;
    const int bl = t >> 4;
    const int gb = blockIdx.x * 16 + bl;

    float tokv[EE];
    {
        const uint4* tp = (const uint4*)(tokb + ((size_t)gb*FF + (size_t)f)*(EE/2));
        uint4 u0 = tp[0], u1 = tp[1];
        tokv[0]  = bflo(u0.x); tokv[1]  = bfhi(u0.x);
        tokv[2]  = bflo(u0.y); tokv[3]  = bfhi(u0.y);
        tokv[4]  = bflo(u0.z); tokv[5]  = bfhi(u0.z);
        tokv[6]  = bflo(u0.w); tokv[7]  = bfhi(u0.w);
        tokv[8]  = bflo(u1.x); tokv[9]  = bfhi(u1.x);
        tokv[10] = bflo(u1.y); tokv[11] = bfhi(u1.y);
        tokv[12] = bflo(u1.z); tokv[13] = bfhi(u1.z);
        tokv[14] = bflo(u1.w); tokv[15] = bfhi(u1.w);
    }

    float q[EE], kx[EE];
    #pragma unroll
    for (int i = 0; i < EE; ++i) { q[i] = bqkv[i]; kx[i] = bqkv[EE + i]; }
    #pragma unroll
    for (int e = 0; e < EE; ++e) {
        const float tv = tokv[e];
        #pragma unroll
        for (int i = 0; i < EE; ++i) {
            q[i]  = fmaf(tv, Wqkv[e*48 + i],      q[i]);
            kx[i] = fmaf(tv, Wqkv[e*48 + EE + i], kx[i]);
        }
    }
    {
        float4* kr = (float4*)(kb + bl*KVPAD + f*16);
        kr[0] = make_float4(kx[0],  kx[1],  kx[2],  kx[3]);
        kr[1] = make_float4(kx[4],  kx[5],  kx[6],  kx[7]);
        kr[2] = make_float4(kx[8],  kx[9],  kx[10], kx[11]);
        kr[3] = make_float4(kx[12], kx[13], kx[14], kx[15]);
    }

    {
        float vx[EE];
        #pragma unroll
        for (int i = 0; i < EE; ++i) vx[i] = bqkv[2*EE + i];
        #pragma unroll
        for (int e = 0; e < EE; ++e) {
            const float tv = tokv[e];
            #pragma unroll
            for (int i = 0; i < EE; ++i)
                vx[i] = fmaf(tv, Wqkv[e*48 + 2*EE + i], vx[i]);
        }
        float4* vr = (float4*)(vb + bl*KVPAD + f*16);
        vr[0] = make_float4(vx[0],  vx[1],  vx[2],  vx[3]);
        vr[1] = make_float4(vx[4],  vx[5],  vx[6],  vx[7]);
        vr[2] = make_float4(vx[8],  vx[9],  vx[10], vx[11]);
        vr[3] = make_float4(vx[12], vx[13], vx[14], vx[15]);
    }

    float s[16];
    #pragma unroll
    for (int kk = 0; kk < 16; ++kk) {
        const float4* krow = (const float4*)(kb + bl*KVPAD + kk*16);
        float4 k0 = krow[0], k1 = krow[1], k2 = krow[2], k3 = krow[3];
        float d = q[0]*k0.x  + q[1]*k0.y  + q[2]*k0.z  + q[3]*k0.w
                + q[4]*k1.x  + q[5]*k1.y  + q[6]*k1.z  + q[7]*k1.w
                + q[8]*k2.x  + q[9]*k2.y  + q[10]*k2.z + q[11]*k2.w
                + q[12]*k3.x + q[13]*k3.y + q[14]*k3.z + q[15]*k3.w;
        s[kk] = d * 0.25f;
    }

    float m = s[0];
    #pragma unroll
    for (int kk = 1; kk < 16; ++kk) m = fmaxf(m, s[kk]);
    float sum = 0.f;
    #pragma unroll
    for (int kk = 0; kk < 16; ++kk) { s[kk] = __expf(s[kk] - m); sum += s[kk]; }
    const float inv = 1.0f / sum;
    #pragma unroll
    for (int kk = 0; kk < 16; ++kk) s[kk] *= inv;

    #pragma unroll
    for (int kk = 0; kk < 16; ++kk) s[kk] = sum16(s[kk]);

    float pvf = 0.f;
    #pragma unroll
    for (int kk = 0; kk < 16; ++kk)
        pvf = fmaf(s[kk], vb[bl*KVPAD + kk*16 + f], pvf);
    pvf *= 0.0625f;

    float wof;
    {
        const float4* wr = (const float4*)(Wo + f*EE);
        float4 w0 = wr[0], w1 = wr[1], w2 = wr[2], w3 = wr[3];
        wof = w0.x*Wf[0]  + w0.y*Wf[1]  + w0.z*Wf[2]  + w0.w*Wf[3]
            + w1.x*Wf[4]  + w1.y*Wf[5]  + w1.z*Wf[6]  + w1.w*Wf[7]
            + w2.x*Wf[8]  + w2.y*Wf[9]  + w2.z*Wf[10] + w2.w*Wf[11]
            + w3.x*Wf[12] + w3.y*Wf[13] + w3.z*Wf[14] + w3.w*Wf[15];
    }

    float c = fmaf(pvf, wof, bo[f]*Wf[f]);
    c = sum16(c);

    if (f == 0) {
        float r = c + bf[0];
        out[gb] = (r >= 0.f) ? r : 0.01f*r;
    }
}

extern "C" void kernel_launch(void* const* d_in, const int* in_sizes, int n_in,
                              void* d_out, int out_size, void* d_ws, size_t ws_size,
                              hipStream_t stream)
{
    const float* x    = (const float*)d_in[0];
    const float* W1   = (const float*)d_in[1];
    const float* b1   = (const float*)d_in[2];
    const float* W2   = (const float*)d_in[3];
    const float* b2   = (const float*)d_in[4];
    const float* W3   = (const float*)d_in[5];
    const float* b3   = (const float*)d_in[6];
    const float* Wp   = (const float*)d_in[7];
    const float* bp   = (const float*)d_in[8];
    const float* Wqkv = (const float*)d_in[9];
    const float* bqkv = (const float*)d_in[10];
    const float* Wo   = (const float*)d_in[11];
    const float* bo   = (const float*)d_in[12];
    const float* Wf   = (const float*)d_in[13];
    const float* bf   = (const float*)d_in[14];
    float* out = (float*)d_out;

    // d_ws: [0,16MiB) tok bf16 [B][F][E]; +16MiB: w2h (128KB), w3ph (32KB), bp3
    unsigned short* tokb16 = (unsigned short*)d_ws;
    unsigned* tokb = (unsigned*)d_ws;
    uint4* w2h  = (uint4*)((char*)d_ws + (16u << 20));
    uint4* w3ph = (uint4*)((char*)d_ws + (16u << 20) + (128u << 10));
    float* bp3  = (float*)((char*)d_ws + (16u << 20) + (160u << 10));

    prepack_kernel<<<FF, 256, 0, stream>>>(W2, W3, b3, Wp, bp, w2h, w3ph, bp3);
    spinn_subnet_mfma<<<dim3(BB/64 * FF), 256, 0, stream>>>(
        x, W1, b1, b2, w2h, w3ph, bp3, tokb16);
    spinn_attn_kernel<<<BB/16, 256, 0, stream>>>(tokb, Wqkv, bqkv, Wo, bo, Wf, bf, out);
}